// Round 10
// baseline (3621.844 us; speedup 1.0000x reference)
//
#include <hip/hip_runtime.h>
#include <hip/hip_bf16.h>

typedef unsigned short u16;
typedef unsigned int   u32;
typedef unsigned long long u64;

typedef __attribute__((ext_vector_type(8))) short short8;
typedef __attribute__((ext_vector_type(4))) float f32x4;
typedef __attribute__((ext_vector_type(4))) u32   u32x4;
typedef __attribute__((ext_vector_type(2))) u32   u32x2;

#define TT 1024
#define HH 512
#define BB 64
#define GCOLS 8
#define LDSK 528   // 264 dwords ≡ 8 mod 32 banks: 4-way on b128 (measured best: 1.7e7 cyc)

// h exchange (LLC): u64 [2 parity][8 group][8 col][256 row-pair]
// u64 = tag<<32 | h[2rp+1]<<16 | h[2rp];  tag for h produced at end of step t is t+1
#define HTB_PAR 16384
#define HTB_GRP 2048
// summary: u32 [2 parity][8 group][32 wg][4 wave], value = t+1 (monotone)
#define DSUM_PAR 1024

__device__ __forceinline__ u16 f2bf(float f) {
    union { float f; u32 u; } v; v.f = f;
    u32 u = v.u;
    return (u16)((u + 0x7FFFu + ((u >> 16) & 1u)) >> 16);
}

__device__ __forceinline__ short8 cvt8(const float4 &a, const float4 &b) {
    short8 r;
    r[0] = (short)f2bf(a.x); r[1] = (short)f2bf(a.y);
    r[2] = (short)f2bf(a.z); r[3] = (short)f2bf(a.w);
    r[4] = (short)f2bf(b.x); r[5] = (short)f2bf(b.y);
    r[6] = (short)f2bf(b.z); r[7] = (short)f2bf(b.w);
    return r;
}

__device__ __forceinline__ float fast_rcp(float x) {
    float r; asm("v_rcp_f32 %0, %1" : "=v"(r) : "v"(x)); return r;
}
__device__ __forceinline__ float fast_sigmoid(float x) { return fast_rcp(1.f + __expf(-x)); }
__device__ __forceinline__ float fast_tanh(float x) {
    float e = __expf(2.f * x);
    return 1.f - 2.f * fast_rcp(e + 1.f);
}

// quad flag spin, monotonic (flag >= want); all lanes read same values (broadcast)
__device__ __forceinline__ void quad_spin(const u32* fl, int qb, u32 want) {
    u32 f0, f1, f2, f3;
    do {
        f0 = __hip_atomic_load(&fl[qb + 0], __ATOMIC_RELAXED, __HIP_MEMORY_SCOPE_WORKGROUP);
        f1 = __hip_atomic_load(&fl[qb + 1], __ATOMIC_RELAXED, __HIP_MEMORY_SCOPE_WORKGROUP);
        f2 = __hip_atomic_load(&fl[qb + 2], __ATOMIC_RELAXED, __HIP_MEMORY_SCOPE_WORKGROUP);
        f3 = __hip_atomic_load(&fl[qb + 3], __ATOMIC_RELAXED, __HIP_MEMORY_SCOPE_WORKGROUP);
    } while (((int)(f0 - want) | (int)(f1 - want) | (int)(f2 - want) | (int)(f3 - want)) < 0);
    asm volatile("" ::: "memory");
}

// 4 chunk polls (16B each, 128B apart), LLC scope
__device__ __forceinline__ void poll_issue(const u64* p, u32x4 &A, u32x4 &B, u32x4 &C, u32x4 &D) {
    asm volatile(
        "global_load_dwordx4 %0, %4, off sc0 sc1\n\t"
        "global_load_dwordx4 %1, %4, off offset:128 sc0 sc1\n\t"
        "global_load_dwordx4 %2, %4, off offset:256 sc0 sc1\n\t"
        "global_load_dwordx4 %3, %4, off offset:384 sc0 sc1"
        : "=&v"(A), "=&v"(B), "=&v"(C), "=&v"(D) : "v"(p) : "memory");
}
__device__ __forceinline__ void poll_wait(u32x4 &A, u32x4 &B, u32x4 &C, u32x4 &D) {
    asm volatile("s_waitcnt vmcnt(0)" : "+v"(A), "+v"(B), "+v"(C), "+v"(D) :: "memory");
}
__device__ __forceinline__ void store_llc(u64* p, u64 v) {
    asm volatile("global_store_dwordx2 %0, %1, off sc0 sc1" :: "v"(p), "v"(v) : "memory");
}
__device__ __forceinline__ void store_llc32(u32* p, u32 v) {
    asm volatile("global_store_dword %0, %1, off sc0 sc1" :: "v"(p), "v"(v) : "memory");
}
__device__ __forceinline__ void summary_issue(const u32* p, u32x2 &S) {
    asm volatile("global_load_dwordx2 %0, %1, off sc0 sc1" : "=&v"(S) : "v"(p) : "memory");
}
__device__ __forceinline__ void summary_wait(u32x2 &S) {
    asm volatile("s_waitcnt vmcnt(0)" : "+v"(S) :: "memory");
}

__global__ void lstm_prep(u64* htb, u32* dsum) {
    int i = blockIdx.x * 256 + threadIdx.x;
    if (i < 32768)
        __hip_atomic_store(&htb[i], 0ull, __ATOMIC_RELAXED, __HIP_MEMORY_SCOPE_AGENT);
    int j = i - 32768;
    if (j >= 0 && j < 2048)
        __hip_atomic_store(&dsum[j], 0u, __ATOMIC_RELAXED, __HIP_MEMORY_SCOPE_AGENT);
}

__global__ __launch_bounds__(256, 1)
void lstm_persist(const float* __restrict__ in_seq,
                  const float* __restrict__ Wxi, const float* __restrict__ Wxf,
                  const float* __restrict__ Wxo, const float* __restrict__ Wxg,
                  const float* __restrict__ Whi, const float* __restrict__ Whf,
                  const float* __restrict__ Who, const float* __restrict__ Whg,
                  float* __restrict__ out, u64* htb, u32* dsum)
{
    __shared__ u16 xt[2][16][LDSK];    // x B-operand, dbuf; cols 8..15 stay zero
    __shared__ u16 htl[2][16][LDSK];   // h B-operand, dbuf; cols 8..15 stay zero
    __shared__ u32 xflag[16];          // per-chunk: (step whose x is staged) + 1
    __shared__ u32 hflag[16];          // per-chunk: step whose h is staged

    const int tid  = threadIdx.x;
    const int bid  = blockIdx.x;
    const int g    = bid & 7;          // column group
    const int rblk = bid >> 3;         // hidden rows [16*rblk, 16*rblk+16)
    const int wv   = tid >> 6;         // wave id 0..3; owns chunks 4wv..4wv+3 (x and h)
    const int lane = tid & 63;
    const int lrow = lane & 15;        // A tile row / B col
    const int lk8  = (lane >> 4) * 8;

    {   // zero LDS once
        u16* p0 = &xt[0][0][0]; u16* p1 = &htl[0][0][0];
        for (int i = tid; i < 2 * 16 * LDSK; i += 256) { p0[i] = 0; p1[i] = 0; }
        if (tid < 16) { xflag[tid] = 1; hflag[tid] = 0; }
    }

    // gate-interleaved A: tile row m = 4q + r -> hidden row wv*4+q, gate r.
    // BOTH halves loaded in wave-rotated chunk order: afrag[4J+i] (x) and
    // afrag[16+4J+i] (h) hold chunk 4*((wv+J)&3)+i  -> compile-time reg indices.
    const int gt   = lrow & 3;
    const int grow = rblk * 16 + wv * 4 + (lrow >> 2);
    const float* WxS = (gt == 0) ? Wxi : (gt == 1) ? Wxf : (gt == 2) ? Wxo : Wxg;
    const float* WhS = (gt == 0) ? Whi : (gt == 1) ? Whf : (gt == 2) ? Who : Whg;

    short8 afrag[32];
    #pragma unroll
    for (int J = 0; J < 4; ++J)
        #pragma unroll
        for (int i = 0; i < 4; ++i) {
            int kk = 4 * ((wv + J) & 3) + i;
            const float* sx = WxS + grow * HH + kk * 32 + lk8;
            const float* sh = WhS + grow * HH + kk * 32 + lk8;
            afrag[4 * J + i]      = cvt8(*(const float4*)sx, *(const float4*)(sx + 4));
            afrag[16 + 4 * J + i] = cvt8(*(const float4*)sh, *(const float4*)(sh + 4));
        }

    const int q    = lane >> 4;        // elementwise: hidden row wv*4+q
    const int colv = lrow;             // elementwise: batch col (valid < 8)
    const int hid  = rblk * 16 + wv * 4 + q;
    float cst = 0.f;
    float hv_prev = 0.f;

    // poll ownership: wave wv polls chunks 4wv..4wv+3; lane covers col pc, rp 2pm(+1)
    const int pc    = lane >> 3;
    const int pm    = lane & 7;
    const int poffb = g * HTB_GRP + pc * 256 + 64 * wv + 2 * pm;
    const int doff  = g * HTB_GRP + colv * 256 + (hid >> 1);
    const int dsoff = g * 128 + rblk * 4 + wv;        // producer done-word
    const int ssoff = g * 128 + lane * 2;             // consumer summary slice

    // ---- prologue: sync-load + stage x_0; issue x_1 into set A ----
    float4 xA0, xA1, xA2, xA3, xB0, xB1, xB2, xB3;
    {
        const float* xb = in_seq + (size_t)(tid * 2) * BB + g * GCOLS;
        float4 c0 = *(const float4*)(xb);      float4 c1 = *(const float4*)(xb + 4);
        float4 c2 = *(const float4*)(xb + BB); float4 c3 = *(const float4*)(xb + BB + 4);
        int k = tid * 2;
        const float *ra = (const float*)&c0, *rb = (const float*)&c2;
        #pragma unroll
        for (int j = 0; j < 4; ++j)
            *(u32*)&xt[0][j][k] = (u32)f2bf(ra[j]) | ((u32)f2bf(rb[j]) << 16);
        const float *ra1 = (const float*)&c1, *rb1 = (const float*)&c3;
        #pragma unroll
        for (int j = 0; j < 4; ++j)
            *(u32*)&xt[0][4 + j][k] = (u32)f2bf(ra1[j]) | ((u32)f2bf(rb1[j]) << 16);
    }
    __syncthreads();   // one prologue barrier: LDS zero + x_0 + flags visible
    {
        const float* xb = in_seq + (size_t)(HH * BB) + (size_t)(tid * 2) * BB + g * GCOLS;
        xA0 = *(const float4*)(xb);      xA1 = *(const float4*)(xb + 4);
        xA2 = *(const float4*)(xb + BB); xA3 = *(const float4*)(xb + BB + 4);
    }

#define LSTM_STEP(T, RIN0, RIN1, RIN2, RIN3, ROUT0, ROUT1, ROUT2, ROUT3)                      \
    {                                                                                         \
        const int t_ = (T);                                                                   \
        const int par_ = t_ & 1;                                                              \
        /* (a0) issue summary poll early: its round trip hides under the x-MFMAs */           \
        u32x2 sum;                                                                            \
        const u32* sp_ = dsum + par_ * DSUM_PAR + ssoff;                                      \
        if (t_ > 0) summary_issue(sp_, sum);                                                  \
        /* (a) x-half MFMAs, quad flag-gated (own quad J=0 skips spin) */                     \
        f32x4 aA = {0.f,0.f,0.f,0.f}, aB = {0.f,0.f,0.f,0.f};                                 \
        {                                                                                     \
            const u32 wantx = (u32)(t_ + 1);                                                  \
            const u16 (*xc)[LDSK] = xt[par_];                                                 \
            _Pragma("unroll")                                                                 \
            for (int J = 0; J < 4; ++J) {                                                     \
                const int qb = 4 * ((wv + J) & 3);                                            \
                if (J > 0) quad_spin(xflag, qb, wantx);                                       \
                short8 b0 = *(const short8*)&xc[lrow][(qb + 0) * 32 + lk8];                   \
                short8 b1 = *(const short8*)&xc[lrow][(qb + 1) * 32 + lk8];                   \
                short8 b2 = *(const short8*)&xc[lrow][(qb + 2) * 32 + lk8];                   \
                short8 b3 = *(const short8*)&xc[lrow][(qb + 3) * 32 + lk8];                   \
                aA = __builtin_amdgcn_mfma_f32_16x16x32_bf16(afrag[4*J+0], b0, aA, 0, 0, 0);  \
                aB = __builtin_amdgcn_mfma_f32_16x16x32_bf16(afrag[4*J+1], b1, aB, 0, 0, 0);  \
                aA = __builtin_amdgcn_mfma_f32_16x16x32_bf16(afrag[4*J+2], b2, aA, 0, 0, 0);  \
                aB = __builtin_amdgcn_mfma_f32_16x16x32_bf16(afrag[4*J+3], b3, aB, 0, 0, 0);  \
            }                                                                                 \
        }                                                                                     \
        /* (b) summary gate (cheap spin), then tagged data rounds; deferred out store */      \
        if (t_ > 0) {                                                                         \
            const u32 want = (u32)t_;                                                         \
            summary_wait(sum);                                                                \
            while (!__all((((int)(sum[0] - want)) | ((int)(sum[1] - want))) >= 0)) {          \
                summary_issue(sp_, sum);                                                      \
                summary_wait(sum);                                                            \
            }                                                                                 \
            const u64* p_ = htb + par_ * HTB_PAR + poffb;                                     \
            int pend = 0xF;                                                                   \
            do {                                                                              \
                u32x4 v0, v1, v2, v3;                                                         \
                poll_issue(p_, v0, v1, v2, v3);                                               \
                poll_wait(v0, v1, v2, v3);                                                    \
                int newly = 0;                                                                \
                if ((pend & 1) && __all((v0[1] == want) & (v0[3] == want))) {                 \
                    *(u64*)&htl[par_][pc][32*(4*wv+0) + 4*pm] = (u64)v0[0] | ((u64)v0[2] << 32); newly |= 1; } \
                if ((pend & 2) && __all((v1[1] == want) & (v1[3] == want))) {                 \
                    *(u64*)&htl[par_][pc][32*(4*wv+1) + 4*pm] = (u64)v1[0] | ((u64)v1[2] << 32); newly |= 2; } \
                if ((pend & 4) && __all((v2[1] == want) & (v2[3] == want))) {                 \
                    *(u64*)&htl[par_][pc][32*(4*wv+2) + 4*pm] = (u64)v2[0] | ((u64)v2[2] << 32); newly |= 4; } \
                if ((pend & 8) && __all((v3[1] == want) & (v3[3] == want))) {                 \
                    *(u64*)&htl[par_][pc][32*(4*wv+3) + 4*pm] = (u64)v3[0] | ((u64)v3[2] << 32); newly |= 8; } \
                if (newly) {                                                                  \
                    asm volatile("s_waitcnt lgkmcnt(0)" ::: "memory");                        \
                    if (lane == 0) {                                                          \
                        if (newly & 1) __hip_atomic_store(&hflag[4*wv+0], want, __ATOMIC_RELAXED, __HIP_MEMORY_SCOPE_WORKGROUP); \
                        if (newly & 2) __hip_atomic_store(&hflag[4*wv+1], want, __ATOMIC_RELAXED, __HIP_MEMORY_SCOPE_WORKGROUP); \
                        if (newly & 4) __hip_atomic_store(&hflag[4*wv+2], want, __ATOMIC_RELAXED, __HIP_MEMORY_SCOPE_WORKGROUP); \
                        if (newly & 8) __hip_atomic_store(&hflag[4*wv+3], want, __ATOMIC_RELAXED, __HIP_MEMORY_SCOPE_WORKGROUP); \
                    }                                                                         \
                    pend &= ~newly;                                                           \
                }                                                                             \
            } while (pend);                                                                   \
            if (colv < 8)                                                                     \
                out[(size_t)(t_ - 1) * (HH * BB) + hid * BB + g * GCOLS + colv] = hv_prev;    \
        }                                                                                     \
        /* (c) issue x_{t+2} loads into the other reg set */                                  \
        if (t_ + 2 < TT) {                                                                    \
            const float* xb_ = in_seq + (size_t)(t_ + 2) * (HH * BB)                          \
                             + (size_t)(tid * 2) * BB + g * GCOLS;                            \
            ROUT0 = *(const float4*)(xb_);      ROUT1 = *(const float4*)(xb_ + 4);            \
            ROUT2 = *(const float4*)(xb_ + BB); ROUT3 = *(const float4*)(xb_ + BB + 4);       \
        }                                                                                     \
        /* (d) h-half MFMAs, quad flag-gated */                                               \
        f32x4 aC = {0.f,0.f,0.f,0.f}, aD = {0.f,0.f,0.f,0.f};                                 \
        if (t_ > 0) {                                                                         \
            const u32 want = (u32)t_;                                                         \
            const u16 (*hc)[LDSK] = htl[par_];                                                \
            _Pragma("unroll")                                                                 \
            for (int J = 0; J < 4; ++J) {                                                     \
                const int qb = 4 * ((wv + J) & 3);                                            \
                if (J > 0) quad_spin(hflag, qb, want);                                        \
                short8 b0 = *(const short8*)&hc[lrow][(qb + 0) * 32 + lk8];                   \
                short8 b1 = *(const short8*)&hc[lrow][(qb + 1) * 32 + lk8];                   \
                short8 b2 = *(const short8*)&hc[lrow][(qb + 2) * 32 + lk8];                   \
                short8 b3 = *(const short8*)&hc[lrow][(qb + 3) * 32 + lk8];                   \
                aC = __builtin_amdgcn_mfma_f32_16x16x32_bf16(afrag[16+4*J+0], b0, aC, 0, 0, 0); \
                aD = __builtin_amdgcn_mfma_f32_16x16x32_bf16(afrag[16+4*J+1], b1, aD, 0, 0, 0); \
                aC = __builtin_amdgcn_mfma_f32_16x16x32_bf16(afrag[16+4*J+2], b2, aC, 0, 0, 0); \
                aD = __builtin_amdgcn_mfma_f32_16x16x32_bf16(afrag[16+4*J+3], b3, aD, 0, 0, 0); \
            }                                                                                 \
        }                                                                                     \
        f32x4 acc = (aA + aB) + (aC + aD);                                                    \
        /* (e) elementwise in-register; tagged h store */                                     \
        if (colv < 8) {                                                                       \
            float iv = fast_sigmoid(acc[0]);                                                  \
            float fv = fast_sigmoid(acc[1]);                                                  \
            float ov = fast_sigmoid(acc[2]);                                                  \
            float gv = fast_tanh(acc[3]);                                                     \
            cst = fv * cst + iv * gv;                                                         \
            float hv = ov * fast_tanh(cst);                                                   \
            u16 hb = f2bf(hv);                                                                \
            u32 up = (u32)__shfl_down((int)(u32)hb, 16);                                      \
            if ((q & 1) == 0) {                                                               \
                u64 pack = ((u64)(u32)(t_ + 1) << 32) | ((u64)(up & 0xffffu) << 16) | (u64)hb;\
                store_llc(htb + ((t_ + 1) & 1) * HTB_PAR + doff, pack);                       \
            }                                                                                 \
            hv_prev = hv;                                                                     \
            if (t_ == TT - 1) {                                                               \
                size_t base_ = (size_t)TT * HH * BB;                                          \
                out[base_ + hid * BB + g * GCOLS + colv] = hv;                                \
                out[base_ + HH * BB + hid * BB + g * GCOLS + colv] = cst;                     \
            }                                                                                 \
        }                                                                                     \
        /* (e2) per-wave done-word: issued after the data stores (program order) */           \
        if (lane == 0)                                                                        \
            store_llc32(dsum + ((t_ + 1) & 1) * DSUM_PAR + dsoff, (u32)(t_ + 1));             \
        /* (f) stage x_{t+1} from RIN (loaded one step ago); set own xflags */                \
        if (t_ + 1 < TT) {                                                                    \
            int k = tid * 2;                                                                  \
            u16 (*xn)[LDSK] = xt[(t_ + 1) & 1];                                               \
            const float *ra = (const float*)&RIN0, *rb = (const float*)&RIN2;                 \
            _Pragma("unroll")                                                                 \
            for (int j = 0; j < 4; ++j)                                                       \
                *(u32*)&xn[j][k] = (u32)f2bf(ra[j]) | ((u32)f2bf(rb[j]) << 16);               \
            const float *ra1 = (const float*)&RIN1, *rb1 = (const float*)&RIN3;               \
            _Pragma("unroll")                                                                 \
            for (int j = 0; j < 4; ++j)                                                       \
                *(u32*)&xn[4 + j][k] = (u32)f2bf(ra1[j]) | ((u32)f2bf(rb1[j]) << 16);         \
            asm volatile("s_waitcnt lgkmcnt(0)" ::: "memory");                                \
            if (lane == 0) {                                                                  \
                u32 nf = (u32)(t_ + 2);                                                       \
                __hip_atomic_store(&xflag[4*wv+0], nf, __ATOMIC_RELAXED, __HIP_MEMORY_SCOPE_WORKGROUP); \
                __hip_atomic_store(&xflag[4*wv+1], nf, __ATOMIC_RELAXED, __HIP_MEMORY_SCOPE_WORKGROUP); \
                __hip_atomic_store(&xflag[4*wv+2], nf, __ATOMIC_RELAXED, __HIP_MEMORY_SCOPE_WORKGROUP); \
                __hip_atomic_store(&xflag[4*wv+3], nf, __ATOMIC_RELAXED, __HIP_MEMORY_SCOPE_WORKGROUP); \
            }                                                                                 \
        }                                                                                     \
    }

    for (int t = 0; t < TT; t += 2) {
        LSTM_STEP(t,     xA0, xA1, xA2, xA3, xB0, xB1, xB2, xB3)
        LSTM_STEP(t + 1, xB0, xB1, xB2, xB3, xA0, xA1, xA2, xA3)
    }
#undef LSTM_STEP

    // flush deferred out[TT-1]
    if (colv < 8)
        out[(size_t)(TT - 1) * (HH * BB) + hid * BB + g * GCOLS + colv] = hv_prev;
}

extern "C" void kernel_launch(void* const* d_in, const int* in_sizes, int n_in,
                              void* d_out, int out_size, void* d_ws, size_t ws_size,
                              hipStream_t stream)
{
    const float* in_seq = (const float*)d_in[0];
    const float* Wxi = (const float*)d_in[1];
    const float* Wxf = (const float*)d_in[2];
    const float* Wxo = (const float*)d_in[3];
    const float* Wxg = (const float*)d_in[4];
    const float* Whi = (const float*)d_in[5];
    const float* Whf = (const float*)d_in[6];
    const float* Who = (const float*)d_in[7];
    const float* Whg = (const float*)d_in[8];

    u64* htb  = (u64*)d_ws;                       // 2*16384 u64 = 256 KiB, LLC-resident
    u32* dsum = (u32*)((u64*)d_ws + 2 * HTB_PAR); // 2048 u32 = 8 KiB done-words

    lstm_prep<<<136, 256, 0, stream>>>(htb, dsum);  // re-zero tags+flags every call
    lstm_persist<<<256, 256, 0, stream>>>(in_seq, Wxi, Wxf, Wxo, Wxg,
                                          Whi, Whf, Who, Whg,
                                          (float*)d_out, htb, dsum);
}

// Round 11
// 3582.274 us; speedup vs baseline: 1.0110x; 1.0110x over previous
//
#include <hip/hip_runtime.h>
#include <hip/hip_bf16.h>

typedef unsigned short u16;
typedef unsigned int   u32;
typedef unsigned long long u64;

typedef __attribute__((ext_vector_type(8))) short short8;
typedef __attribute__((ext_vector_type(4))) float f32x4;
typedef __attribute__((ext_vector_type(4))) u32   u32x4;

#define TT 1024
#define HH 512
#define BB 64
#define GCOLS 8
#define LDSK 528   // 264 dwords ≡ 8 mod 32 banks: 4-way on b128 (measured best: 1.7e7 cyc)

// h exchange (LLC): u64 [2 parity][8 group][8 col][256 row-pair]
// u64 = tag<<32 | h[2rp+1]<<16 | h[2rp];  tag for h produced at end of step t is t+1
#define HTB_PAR 16384
#define HTB_GRP 2048

__device__ __forceinline__ u16 f2bf(float f) {
    union { float f; u32 u; } v; v.f = f;
    u32 u = v.u;
    return (u16)((u + 0x7FFFu + ((u >> 16) & 1u)) >> 16);
}

__device__ __forceinline__ short8 cvt8(const float4 &a, const float4 &b) {
    short8 r;
    r[0] = (short)f2bf(a.x); r[1] = (short)f2bf(a.y);
    r[2] = (short)f2bf(a.z); r[3] = (short)f2bf(a.w);
    r[4] = (short)f2bf(b.x); r[5] = (short)f2bf(b.y);
    r[6] = (short)f2bf(b.z); r[7] = (short)f2bf(b.w);
    return r;
}

__device__ __forceinline__ float fast_rcp(float x) {
    float r; asm("v_rcp_f32 %0, %1" : "=v"(r) : "v"(x)); return r;
}
__device__ __forceinline__ float fast_sigmoid(float x) { return fast_rcp(1.f + __expf(-x)); }
__device__ __forceinline__ float fast_tanh(float x) {
    float e = __expf(2.f * x);
    return 1.f - 2.f * fast_rcp(e + 1.f);
}

// quad flag spin, monotonic (flag >= want); all lanes read same values (broadcast)
__device__ __forceinline__ void quad_spin(const u32* fl, int qb, u32 want) {
    u32 f0, f1, f2, f3;
    do {
        f0 = __hip_atomic_load(&fl[qb + 0], __ATOMIC_RELAXED, __HIP_MEMORY_SCOPE_WORKGROUP);
        f1 = __hip_atomic_load(&fl[qb + 1], __ATOMIC_RELAXED, __HIP_MEMORY_SCOPE_WORKGROUP);
        f2 = __hip_atomic_load(&fl[qb + 2], __ATOMIC_RELAXED, __HIP_MEMORY_SCOPE_WORKGROUP);
        f3 = __hip_atomic_load(&fl[qb + 3], __ATOMIC_RELAXED, __HIP_MEMORY_SCOPE_WORKGROUP);
    } while (((int)(f0 - want) | (int)(f1 - want) | (int)(f2 - want) | (int)(f3 - want)) < 0);
    asm volatile("" ::: "memory");
}

// 4 chunk polls (16B each, 128B apart), LLC scope
__device__ __forceinline__ void poll_issue(const u64* p, u32x4 &A, u32x4 &B, u32x4 &C, u32x4 &D) {
    asm volatile(
        "global_load_dwordx4 %0, %4, off sc0 sc1\n\t"
        "global_load_dwordx4 %1, %4, off offset:128 sc0 sc1\n\t"
        "global_load_dwordx4 %2, %4, off offset:256 sc0 sc1\n\t"
        "global_load_dwordx4 %3, %4, off offset:384 sc0 sc1"
        : "=&v"(A), "=&v"(B), "=&v"(C), "=&v"(D) : "v"(p) : "memory");
}
__device__ __forceinline__ void poll_wait(u32x4 &A, u32x4 &B, u32x4 &C, u32x4 &D) {
    asm volatile("s_waitcnt vmcnt(0)" : "+v"(A), "+v"(B), "+v"(C), "+v"(D) :: "memory");
}
__device__ __forceinline__ void store_llc(u64* p, u64 v) {
    asm volatile("global_store_dwordx2 %0, %1, off sc0 sc1" :: "v"(p), "v"(v) : "memory");
}

__global__ void lstm_prep(u64* htb) {
    int i = blockIdx.x * 256 + threadIdx.x;   // 128*256 = 32768 u64 = full buffer
    __hip_atomic_store(&htb[i], 0ull, __ATOMIC_RELAXED, __HIP_MEMORY_SCOPE_AGENT);
}

__global__ __launch_bounds__(256, 1)
void lstm_persist(const float* __restrict__ in_seq,
                  const float* __restrict__ Wxi, const float* __restrict__ Wxf,
                  const float* __restrict__ Wxo, const float* __restrict__ Wxg,
                  const float* __restrict__ Whi, const float* __restrict__ Whf,
                  const float* __restrict__ Who, const float* __restrict__ Whg,
                  float* __restrict__ out, u64* htb)
{
    __shared__ u16 xt[2][16][LDSK];    // x B-operand, dbuf; cols 8..15 stay zero
    __shared__ u16 htl[2][16][LDSK];   // h B-operand, dbuf; cols 8..15 stay zero
    __shared__ u32 xflag[16];          // per-chunk: (step whose x is staged) + 1
    __shared__ u32 hflag[16];          // per-chunk: step whose h is staged

    const int tid  = threadIdx.x;
    const int bid  = blockIdx.x;
    const int g    = bid & 7;          // column group
    const int rblk = bid >> 3;         // hidden rows [16*rblk, 16*rblk+16)
    const int wv   = tid >> 6;         // wave id 0..3; owns chunks 4wv..4wv+3 (x and h)
    const int lane = tid & 63;
    const int lrow = lane & 15;        // A tile row / B col
    const int lk8  = (lane >> 4) * 8;

    {   // zero LDS once
        u16* p0 = &xt[0][0][0]; u16* p1 = &htl[0][0][0];
        for (int i = tid; i < 2 * 16 * LDSK; i += 256) { p0[i] = 0; p1[i] = 0; }
        if (tid < 16) { xflag[tid] = 1; hflag[tid] = 0; }
    }

    // gate-interleaved A: tile row m = 4q + r -> hidden row wv*4+q, gate r.
    // BOTH halves loaded in wave-rotated chunk order: afrag[4J+i] (x) and
    // afrag[16+4J+i] (h) hold chunk 4*((wv+J)&3)+i  -> compile-time reg indices.
    const int gt   = lrow & 3;
    const int grow = rblk * 16 + wv * 4 + (lrow >> 2);
    const float* WxS = (gt == 0) ? Wxi : (gt == 1) ? Wxf : (gt == 2) ? Wxo : Wxg;
    const float* WhS = (gt == 0) ? Whi : (gt == 1) ? Whf : (gt == 2) ? Who : Whg;

    short8 afrag[32];
    #pragma unroll
    for (int J = 0; J < 4; ++J)
        #pragma unroll
        for (int i = 0; i < 4; ++i) {
            int kk = 4 * ((wv + J) & 3) + i;
            const float* sx = WxS + grow * HH + kk * 32 + lk8;
            const float* sh = WhS + grow * HH + kk * 32 + lk8;
            afrag[4 * J + i]      = cvt8(*(const float4*)sx, *(const float4*)(sx + 4));
            afrag[16 + 4 * J + i] = cvt8(*(const float4*)sh, *(const float4*)(sh + 4));
        }

    const int q    = lane >> 4;        // elementwise: hidden row wv*4+q
    const int colv = lrow;             // elementwise: batch col (valid < 8)
    const int hid  = rblk * 16 + wv * 4 + q;
    float cst = 0.f;
    float hv_prev = 0.f;

    // poll ownership: wave wv polls chunks 4wv..4wv+3; lane covers col pc, rp 2pm(+1)
    const int pc    = lane >> 3;
    const int pm    = lane & 7;
    const int poffb = g * HTB_GRP + pc * 256 + 64 * wv + 2 * pm;
    const int doff  = g * HTB_GRP + colv * 256 + (hid >> 1);

    // ---- prologue: sync-load + stage x_0; issue x_1 into set A ----
    float4 xA0, xA1, xA2, xA3, xB0, xB1, xB2, xB3;
    {
        const float* xb = in_seq + (size_t)(tid * 2) * BB + g * GCOLS;
        float4 c0 = *(const float4*)(xb);      float4 c1 = *(const float4*)(xb + 4);
        float4 c2 = *(const float4*)(xb + BB); float4 c3 = *(const float4*)(xb + BB + 4);
        int k = tid * 2;
        const float *ra = (const float*)&c0, *rb = (const float*)&c2;
        #pragma unroll
        for (int j = 0; j < 4; ++j)
            *(u32*)&xt[0][j][k] = (u32)f2bf(ra[j]) | ((u32)f2bf(rb[j]) << 16);
        const float *ra1 = (const float*)&c1, *rb1 = (const float*)&c3;
        #pragma unroll
        for (int j = 0; j < 4; ++j)
            *(u32*)&xt[0][4 + j][k] = (u32)f2bf(ra1[j]) | ((u32)f2bf(rb1[j]) << 16);
    }
    __syncthreads();   // one prologue barrier: LDS zero + x_0 + flags visible
    {
        const float* xb = in_seq + (size_t)(HH * BB) + (size_t)(tid * 2) * BB + g * GCOLS;
        xA0 = *(const float4*)(xb);      xA1 = *(const float4*)(xb + 4);
        xA2 = *(const float4*)(xb + BB); xA3 = *(const float4*)(xb + BB + 4);
    }

#define LSTM_STEP(T, RIN0, RIN1, RIN2, RIN3, ROUT0, ROUT1, ROUT2, ROUT3)                      \
    {                                                                                         \
        const int t_ = (T);                                                                   \
        const int par_ = t_ & 1;                                                              \
        const u64* p_ = htb + par_ * HTB_PAR + poffb;                                         \
        /* (a0) issue tagged poll round 1 NOW: round trip hides under the x-MFMA phase */     \
        u32x4 v0, v1, v2, v3;                                                                 \
        if (t_ > 0) poll_issue(p_, v0, v1, v2, v3);                                           \
        /* (a) x-half MFMAs, quad flag-gated (own quad J=0 skips spin) */                     \
        f32x4 aA = {0.f,0.f,0.f,0.f}, aB = {0.f,0.f,0.f,0.f};                                 \
        {                                                                                     \
            const u32 wantx = (u32)(t_ + 1);                                                  \
            const u16 (*xc)[LDSK] = xt[par_];                                                 \
            _Pragma("unroll")                                                                 \
            for (int J = 0; J < 4; ++J) {                                                     \
                const int qb = 4 * ((wv + J) & 3);                                            \
                if (J > 0) quad_spin(xflag, qb, wantx);                                       \
                short8 b0 = *(const short8*)&xc[lrow][(qb + 0) * 32 + lk8];                   \
                short8 b1 = *(const short8*)&xc[lrow][(qb + 1) * 32 + lk8];                   \
                short8 b2 = *(const short8*)&xc[lrow][(qb + 2) * 32 + lk8];                   \
                short8 b3 = *(const short8*)&xc[lrow][(qb + 3) * 32 + lk8];                   \
                aA = __builtin_amdgcn_mfma_f32_16x16x32_bf16(afrag[4*J+0], b0, aA, 0, 0, 0);  \
                aB = __builtin_amdgcn_mfma_f32_16x16x32_bf16(afrag[4*J+1], b1, aB, 0, 0, 0);  \
                aA = __builtin_amdgcn_mfma_f32_16x16x32_bf16(afrag[4*J+2], b2, aA, 0, 0, 0);  \
                aB = __builtin_amdgcn_mfma_f32_16x16x32_bf16(afrag[4*J+3], b3, aB, 0, 0, 0);  \
            }                                                                                 \
        }                                                                                     \
        /* (b) consume round 1; re-poll as needed; stage + hflag; deferred out store */       \
        if (t_ > 0) {                                                                         \
            const u32 want = (u32)t_;                                                         \
            int pend = 0xF;                                                                   \
            poll_wait(v0, v1, v2, v3);                                                        \
            for (;;) {                                                                        \
                int newly = 0;                                                                \
                if ((pend & 1) && __all((v0[1] == want) & (v0[3] == want))) {                 \
                    *(u64*)&htl[par_][pc][32*(4*wv+0) + 4*pm] = (u64)v0[0] | ((u64)v0[2] << 32); newly |= 1; } \
                if ((pend & 2) && __all((v1[1] == want) & (v1[3] == want))) {                 \
                    *(u64*)&htl[par_][pc][32*(4*wv+1) + 4*pm] = (u64)v1[0] | ((u64)v1[2] << 32); newly |= 2; } \
                if ((pend & 4) && __all((v2[1] == want) & (v2[3] == want))) {                 \
                    *(u64*)&htl[par_][pc][32*(4*wv+2) + 4*pm] = (u64)v2[0] | ((u64)v2[2] << 32); newly |= 4; } \
                if ((pend & 8) && __all((v3[1] == want) & (v3[3] == want))) {                 \
                    *(u64*)&htl[par_][pc][32*(4*wv+3) + 4*pm] = (u64)v3[0] | ((u64)v3[2] << 32); newly |= 8; } \
                if (newly) {                                                                  \
                    asm volatile("s_waitcnt lgkmcnt(0)" ::: "memory");                        \
                    if (lane == 0) {                                                          \
                        if (newly & 1) __hip_atomic_store(&hflag[4*wv+0], want, __ATOMIC_RELAXED, __HIP_MEMORY_SCOPE_WORKGROUP); \
                        if (newly & 2) __hip_atomic_store(&hflag[4*wv+1], want, __ATOMIC_RELAXED, __HIP_MEMORY_SCOPE_WORKGROUP); \
                        if (newly & 4) __hip_atomic_store(&hflag[4*wv+2], want, __ATOMIC_RELAXED, __HIP_MEMORY_SCOPE_WORKGROUP); \
                        if (newly & 8) __hip_atomic_store(&hflag[4*wv+3], want, __ATOMIC_RELAXED, __HIP_MEMORY_SCOPE_WORKGROUP); \
                    }                                                                         \
                    pend &= ~newly;                                                           \
                }                                                                             \
                if (!pend) break;                                                             \
                poll_issue(p_, v0, v1, v2, v3);                                               \
                poll_wait(v0, v1, v2, v3);                                                    \
            }                                                                                 \
            if (colv < 8)                                                                     \
                out[(size_t)(t_ - 1) * (HH * BB) + hid * BB + g * GCOLS + colv] = hv_prev;    \
        }                                                                                     \
        /* (c) issue x_{t+2} loads into the other reg set */                                  \
        if (t_ + 2 < TT) {                                                                    \
            const float* xb_ = in_seq + (size_t)(t_ + 2) * (HH * BB)                          \
                             + (size_t)(tid * 2) * BB + g * GCOLS;                            \
            ROUT0 = *(const float4*)(xb_);      ROUT1 = *(const float4*)(xb_ + 4);            \
            ROUT2 = *(const float4*)(xb_ + BB); ROUT3 = *(const float4*)(xb_ + BB + 4);       \
        }                                                                                     \
        /* (d) h-half MFMAs, quad flag-gated */                                               \
        f32x4 aC = {0.f,0.f,0.f,0.f}, aD = {0.f,0.f,0.f,0.f};                                 \
        if (t_ > 0) {                                                                         \
            const u32 want = (u32)t_;                                                         \
            const u16 (*hc)[LDSK] = htl[par_];                                                \
            _Pragma("unroll")                                                                 \
            for (int J = 0; J < 4; ++J) {                                                     \
                const int qb = 4 * ((wv + J) & 3);                                            \
                if (J > 0) quad_spin(hflag, qb, want);                                        \
                short8 b0 = *(const short8*)&hc[lrow][(qb + 0) * 32 + lk8];                   \
                short8 b1 = *(const short8*)&hc[lrow][(qb + 1) * 32 + lk8];                   \
                short8 b2 = *(const short8*)&hc[lrow][(qb + 2) * 32 + lk8];                   \
                short8 b3 = *(const short8*)&hc[lrow][(qb + 3) * 32 + lk8];                   \
                aC = __builtin_amdgcn_mfma_f32_16x16x32_bf16(afrag[16+4*J+0], b0, aC, 0, 0, 0); \
                aD = __builtin_amdgcn_mfma_f32_16x16x32_bf16(afrag[16+4*J+1], b1, aD, 0, 0, 0); \
                aC = __builtin_amdgcn_mfma_f32_16x16x32_bf16(afrag[16+4*J+2], b2, aC, 0, 0, 0); \
                aD = __builtin_amdgcn_mfma_f32_16x16x32_bf16(afrag[16+4*J+3], b3, aD, 0, 0, 0); \
            }                                                                                 \
        }                                                                                     \
        f32x4 acc = (aA + aB) + (aC + aD);                                                    \
        /* (e) elementwise in-register; tagged h store */                                     \
        if (colv < 8) {                                                                       \
            float iv = fast_sigmoid(acc[0]);                                                  \
            float fv = fast_sigmoid(acc[1]);                                                  \
            float ov = fast_sigmoid(acc[2]);                                                  \
            float gv = fast_tanh(acc[3]);                                                     \
            cst = fv * cst + iv * gv;                                                         \
            float hv = ov * fast_tanh(cst);                                                   \
            u16 hb = f2bf(hv);                                                                \
            u32 up = (u32)__shfl_down((int)(u32)hb, 16);                                      \
            if ((q & 1) == 0) {                                                               \
                u64 pack = ((u64)(u32)(t_ + 1) << 32) | ((u64)(up & 0xffffu) << 16) | (u64)hb;\
                store_llc(htb + ((t_ + 1) & 1) * HTB_PAR + doff, pack);                       \
            }                                                                                 \
            hv_prev = hv;                                                                     \
            if (t_ == TT - 1) {                                                               \
                size_t base_ = (size_t)TT * HH * BB;                                          \
                out[base_ + hid * BB + g * GCOLS + colv] = hv;                                \
                out[base_ + HH * BB + hid * BB + g * GCOLS + colv] = cst;                     \
            }                                                                                 \
        }                                                                                     \
        /* (f) stage x_{t+1} from RIN (loaded one step ago); set own xflags */                \
        if (t_ + 1 < TT) {                                                                    \
            int k = tid * 2;                                                                  \
            u16 (*xn)[LDSK] = xt[(t_ + 1) & 1];                                               \
            const float *ra = (const float*)&RIN0, *rb = (const float*)&RIN2;                 \
            _Pragma("unroll")                                                                 \
            for (int j = 0; j < 4; ++j)                                                       \
                *(u32*)&xn[j][k] = (u32)f2bf(ra[j]) | ((u32)f2bf(rb[j]) << 16);               \
            const float *ra1 = (const float*)&RIN1, *rb1 = (const float*)&RIN3;               \
            _Pragma("unroll")                                                                 \
            for (int j = 0; j < 4; ++j)                                                       \
                *(u32*)&xn[4 + j][k] = (u32)f2bf(ra1[j]) | ((u32)f2bf(rb1[j]) << 16);         \
            asm volatile("s_waitcnt lgkmcnt(0)" ::: "memory");                                \
            if (lane == 0) {                                                                  \
                u32 nf = (u32)(t_ + 2);                                                       \
                __hip_atomic_store(&xflag[4*wv+0], nf, __ATOMIC_RELAXED, __HIP_MEMORY_SCOPE_WORKGROUP); \
                __hip_atomic_store(&xflag[4*wv+1], nf, __ATOMIC_RELAXED, __HIP_MEMORY_SCOPE_WORKGROUP); \
                __hip_atomic_store(&xflag[4*wv+2], nf, __ATOMIC_RELAXED, __HIP_MEMORY_SCOPE_WORKGROUP); \
                __hip_atomic_store(&xflag[4*wv+3], nf, __ATOMIC_RELAXED, __HIP_MEMORY_SCOPE_WORKGROUP); \
            }                                                                                 \
        }                                                                                     \
    }

    for (int t = 0; t < TT; t += 2) {
        LSTM_STEP(t,     xA0, xA1, xA2, xA3, xB0, xB1, xB2, xB3)
        LSTM_STEP(t + 1, xB0, xB1, xB2, xB3, xA0, xA1, xA2, xA3)
    }
#undef LSTM_STEP

    // flush deferred out[TT-1]
    if (colv < 8)
        out[(size_t)(TT - 1) * (HH * BB) + hid * BB + g * GCOLS + colv] = hv_prev;
}

extern "C" void kernel_launch(void* const* d_in, const int* in_sizes, int n_in,
                              void* d_out, int out_size, void* d_ws, size_t ws_size,
                              hipStream_t stream)
{
    const float* in_seq = (const float*)d_in[0];
    const float* Wxi = (const float*)d_in[1];
    const float* Wxf = (const float*)d_in[2];
    const float* Wxo = (const float*)d_in[3];
    const float* Wxg = (const float*)d_in[4];
    const float* Whi = (const float*)d_in[5];
    const float* Whf = (const float*)d_in[6];
    const float* Who = (const float*)d_in[7];
    const float* Whg = (const float*)d_in[8];

    u64* htb = (u64*)d_ws;   // 2*16384 u64 = 256 KiB, LLC-resident

    lstm_prep<<<128, 256, 0, stream>>>(htb);   // re-zero tags every call (pre-poison safety)
    lstm_persist<<<256, 256, 0, stream>>>(in_seq, Wxi, Wxf, Wxo, Wxg,
                                          Whi, Whf, Who, Whg,
                                          (float*)d_out, htb);
}

// Round 12
// 2921.096 us; speedup vs baseline: 1.2399x; 1.2263x over previous
//
#include <hip/hip_runtime.h>
#include <hip/hip_bf16.h>

typedef unsigned short u16;
typedef unsigned int   u32;
typedef unsigned long long u64;

typedef __attribute__((ext_vector_type(8))) short short8;
typedef __attribute__((ext_vector_type(4))) float f32x4;
typedef __attribute__((ext_vector_type(4))) u32   u32x4;

#define TT 1024
#define HH 512
#define BB 64
#define GCOLS 8
#define LDSK 528   // 264 dwords ≡ 8 mod 32 banks: 4-way on b128 (measured best: 1.7e7 cyc)

// h exchange (LLC): u64 [2 parity][8 group][8 col][256 row-pair]
// u64 = tag<<32 | h[2rp+1]<<16 | h[2rp];  tag for h produced at end of step t is t+1
#define HTB_PAR 16384
#define HTB_GRP 2048
// done-words: u32 [2 parity][8 group][32 wg][4 wave] = t+1 after wave's h stores are ack'd
#define DSUM_PAR 1024

__device__ __forceinline__ u16 f2bf(float f) {
    union { float f; u32 u; } v; v.f = f;
    u32 u = v.u;
    return (u16)((u + 0x7FFFu + ((u >> 16) & 1u)) >> 16);
}

__device__ __forceinline__ short8 cvt8(const float4 &a, const float4 &b) {
    short8 r;
    r[0] = (short)f2bf(a.x); r[1] = (short)f2bf(a.y);
    r[2] = (short)f2bf(a.z); r[3] = (short)f2bf(a.w);
    r[4] = (short)f2bf(b.x); r[5] = (short)f2bf(b.y);
    r[6] = (short)f2bf(b.z); r[7] = (short)f2bf(b.w);
    return r;
}

__device__ __forceinline__ float fast_rcp(float x) {
    float r; asm("v_rcp_f32 %0, %1" : "=v"(r) : "v"(x)); return r;
}
__device__ __forceinline__ float fast_sigmoid(float x) { return fast_rcp(1.f + __expf(-x)); }
__device__ __forceinline__ float fast_tanh(float x) {
    float e = __expf(2.f * x);
    return 1.f - 2.f * fast_rcp(e + 1.f);
}

// quad flag spin, monotonic (flag >= want); all lanes read same values (broadcast)
__device__ __forceinline__ void quad_spin(const u32* fl, int qb, u32 want) {
    u32 f0, f1, f2, f3;
    do {
        f0 = __hip_atomic_load(&fl[qb + 0], __ATOMIC_RELAXED, __HIP_MEMORY_SCOPE_WORKGROUP);
        f1 = __hip_atomic_load(&fl[qb + 1], __ATOMIC_RELAXED, __HIP_MEMORY_SCOPE_WORKGROUP);
        f2 = __hip_atomic_load(&fl[qb + 2], __ATOMIC_RELAXED, __HIP_MEMORY_SCOPE_WORKGROUP);
        f3 = __hip_atomic_load(&fl[qb + 3], __ATOMIC_RELAXED, __HIP_MEMORY_SCOPE_WORKGROUP);
    } while (((int)(f0 - want) | (int)(f1 - want) | (int)(f2 - want) | (int)(f3 - want)) < 0);
    asm volatile("" ::: "memory");
}

// 4 chunk polls (16B each, 128B apart), LLC scope
__device__ __forceinline__ void poll_issue(const u64* p, u32x4 &A, u32x4 &B, u32x4 &C, u32x4 &D) {
    asm volatile(
        "global_load_dwordx4 %0, %4, off sc0 sc1\n\t"
        "global_load_dwordx4 %1, %4, off offset:128 sc0 sc1\n\t"
        "global_load_dwordx4 %2, %4, off offset:256 sc0 sc1\n\t"
        "global_load_dwordx4 %3, %4, off offset:384 sc0 sc1"
        : "=&v"(A), "=&v"(B), "=&v"(C), "=&v"(D) : "v"(p) : "memory");
}
__device__ __forceinline__ void poll_wait(u32x4 &A, u32x4 &B, u32x4 &C, u32x4 &D) {
    asm volatile("s_waitcnt vmcnt(0)" : "+v"(A), "+v"(B), "+v"(C), "+v"(D) :: "memory");
}
__device__ __forceinline__ void store_llc(u64* p, u64 v) {
    asm volatile("global_store_dwordx2 %0, %1, off sc0 sc1" :: "v"(p), "v"(v) : "memory");
}
__device__ __forceinline__ void store_llc32(u32* p, u32 v) {
    asm volatile("global_store_dword %0, %1, off sc0 sc1" :: "v"(p), "v"(v) : "memory");
}

__global__ void lstm_prep(u64* htb, u32* dsum) {
    int i = blockIdx.x * 256 + threadIdx.x;
    if (i < 32768)
        __hip_atomic_store(&htb[i], 0ull, __ATOMIC_RELAXED, __HIP_MEMORY_SCOPE_AGENT);
    int j = i - 32768;
    if (j >= 0 && j < 2048)
        __hip_atomic_store(&dsum[j], 0u, __ATOMIC_RELAXED, __HIP_MEMORY_SCOPE_AGENT);
}

__global__ __launch_bounds__(256, 1)
void lstm_persist(const float* __restrict__ in_seq,
                  const float* __restrict__ Wxi, const float* __restrict__ Wxf,
                  const float* __restrict__ Wxo, const float* __restrict__ Wxg,
                  const float* __restrict__ Whi, const float* __restrict__ Whf,
                  const float* __restrict__ Who, const float* __restrict__ Whg,
                  float* __restrict__ out, u64* htb, u32* dsum)
{
    __shared__ u16 xt[2][16][LDSK];    // x B-operand, dbuf; cols 8..15 stay zero
    __shared__ u16 htl[2][16][LDSK];   // h B-operand, dbuf; cols 8..15 stay zero
    __shared__ u32 xflag[16];          // per-chunk: (step whose x is staged) + 1
    __shared__ u32 hflag[16];          // per-chunk: step whose h is staged

    const int tid  = threadIdx.x;
    const int bid  = blockIdx.x;
    const int g    = bid & 7;          // column group
    const int rblk = bid >> 3;         // hidden rows [16*rblk, 16*rblk+16)
    const int wv   = tid >> 6;         // wave id 0..3; owns chunks 4wv..4wv+3 (x and h)
    const int lane = tid & 63;
    const int lrow = lane & 15;        // A tile row / B col
    const int lk8  = (lane >> 4) * 8;

    {   // zero LDS once
        u16* p0 = &xt[0][0][0]; u16* p1 = &htl[0][0][0];
        for (int i = tid; i < 2 * 16 * LDSK; i += 256) { p0[i] = 0; p1[i] = 0; }
        if (tid < 16) { xflag[tid] = 1; hflag[tid] = 0; }
    }

    // gate-interleaved A: tile row m = 4q + r -> hidden row wv*4+q, gate r.
    // BOTH halves loaded in wave-rotated chunk order: afrag[4J+i] (x) and
    // afrag[16+4J+i] (h) hold chunk 4*((wv+J)&3)+i  -> compile-time reg indices.
    const int gt   = lrow & 3;
    const int grow = rblk * 16 + wv * 4 + (lrow >> 2);
    const float* WxS = (gt == 0) ? Wxi : (gt == 1) ? Wxf : (gt == 2) ? Wxo : Wxg;
    const float* WhS = (gt == 0) ? Whi : (gt == 1) ? Whf : (gt == 2) ? Who : Whg;

    short8 afrag[32];
    #pragma unroll
    for (int J = 0; J < 4; ++J)
        #pragma unroll
        for (int i = 0; i < 4; ++i) {
            int kk = 4 * ((wv + J) & 3) + i;
            const float* sx = WxS + grow * HH + kk * 32 + lk8;
            const float* sh = WhS + grow * HH + kk * 32 + lk8;
            afrag[4 * J + i]      = cvt8(*(const float4*)sx, *(const float4*)(sx + 4));
            afrag[16 + 4 * J + i] = cvt8(*(const float4*)sh, *(const float4*)(sh + 4));
        }

    const int q    = lane >> 4;        // elementwise: hidden row wv*4+q
    const int colv = lrow;             // elementwise: batch col (valid < 8)
    const int hid  = rblk * 16 + wv * 4 + q;
    float cst = 0.f;
    float hv_prev = 0.f;

    // poll ownership: wave wv polls chunks 4wv..4wv+3; lane covers col pc, rp 2pm(+1)
    const int pc    = lane >> 3;
    const int pm    = lane & 7;
    const int poffb = g * HTB_GRP + pc * 256 + 64 * wv + 2 * pm;
    const int doff  = g * HTB_GRP + colv * 256 + (hid >> 1);
    // summary: consumer wave wv depends on producer WGs 8wv..8wv+7 (x4 waves = 32 words)
    const int ssoff = g * 128 + 32 * wv + (lane & 31);   // lane's watched done-word
    const int dsoff = g * 128 + rblk * 4 + wv;           // this wave's done-word

    // ---- prologue: sync-load + stage x_0; issue x_1 into set A ----
    float4 xA0, xA1, xA2, xA3, xB0, xB1, xB2, xB3;
    {
        const float* xb = in_seq + (size_t)(tid * 2) * BB + g * GCOLS;
        float4 c0 = *(const float4*)(xb);      float4 c1 = *(const float4*)(xb + 4);
        float4 c2 = *(const float4*)(xb + BB); float4 c3 = *(const float4*)(xb + BB + 4);
        int k = tid * 2;
        const float *ra = (const float*)&c0, *rb = (const float*)&c2;
        #pragma unroll
        for (int j = 0; j < 4; ++j)
            *(u32*)&xt[0][j][k] = (u32)f2bf(ra[j]) | ((u32)f2bf(rb[j]) << 16);
        const float *ra1 = (const float*)&c1, *rb1 = (const float*)&c3;
        #pragma unroll
        for (int j = 0; j < 4; ++j)
            *(u32*)&xt[0][4 + j][k] = (u32)f2bf(ra1[j]) | ((u32)f2bf(rb1[j]) << 16);
    }
    __syncthreads();   // one prologue barrier: LDS zero + x_0 + flags visible
    {
        const float* xb = in_seq + (size_t)(HH * BB) + (size_t)(tid * 2) * BB + g * GCOLS;
        xA0 = *(const float4*)(xb);      xA1 = *(const float4*)(xb + 4);
        xA2 = *(const float4*)(xb + BB); xA3 = *(const float4*)(xb + BB + 4);
    }

#define LSTM_STEP(T, RIN0, RIN1, RIN2, RIN3, ROUT0, ROUT1, ROUT2, ROUT3)                      \
    {                                                                                         \
        const int t_ = (T);                                                                   \
        const int par_ = t_ & 1;                                                              \
        /* (a) x-half MFMAs, quad flag-gated (own quad J=0 skips spin) */                     \
        f32x4 aA = {0.f,0.f,0.f,0.f}, aB = {0.f,0.f,0.f,0.f};                                 \
        {                                                                                     \
            const u32 wantx = (u32)(t_ + 1);                                                  \
            const u16 (*xc)[LDSK] = xt[par_];                                                 \
            _Pragma("unroll")                                                                 \
            for (int J = 0; J < 4; ++J) {                                                     \
                const int qb = 4 * ((wv + J) & 3);                                            \
                if (J > 0) quad_spin(xflag, qb, wantx);                                       \
                short8 b0 = *(const short8*)&xc[lrow][(qb + 0) * 32 + lk8];                   \
                short8 b1 = *(const short8*)&xc[lrow][(qb + 1) * 32 + lk8];                   \
                short8 b2 = *(const short8*)&xc[lrow][(qb + 2) * 32 + lk8];                   \
                short8 b3 = *(const short8*)&xc[lrow][(qb + 3) * 32 + lk8];                   \
                aA = __builtin_amdgcn_mfma_f32_16x16x32_bf16(afrag[4*J+0], b0, aA, 0, 0, 0);  \
                aB = __builtin_amdgcn_mfma_f32_16x16x32_bf16(afrag[4*J+1], b1, aB, 0, 0, 0);  \
                aA = __builtin_amdgcn_mfma_f32_16x16x32_bf16(afrag[4*J+2], b2, aA, 0, 0, 0);  \
                aB = __builtin_amdgcn_mfma_f32_16x16x32_bf16(afrag[4*J+3], b3, aB, 0, 0, 0);  \
            }                                                                                 \
        }                                                                                     \
        /* (b) cheap summary spin (128B coalesced broadcast/round, exactly my 32 producer    \
               waves), then tagged data round(s); deferred out store */                       \
        if (t_ > 0) {                                                                         \
            const u32 want = (u32)t_;                                                         \
            const u32* sp_ = dsum + par_ * DSUM_PAR + ssoff;                                  \
            u32 sv;                                                                           \
            do {                                                                              \
                asm volatile("global_load_dword %0, %1, off sc0 sc1\n\t"                      \
                             "s_waitcnt vmcnt(0)" : "=&v"(sv) : "v"(sp_) : "memory");         \
            } while (!__all((int)(sv - want) >= 0));                                          \
            const u64* p_ = htb + par_ * HTB_PAR + poffb;                                     \
            int pend = 0xF;                                                                   \
            do {                                                                              \
                u32x4 v0, v1, v2, v3;                                                         \
                poll_issue(p_, v0, v1, v2, v3);                                               \
                poll_wait(v0, v1, v2, v3);                                                    \
                int newly = 0;                                                                \
                if ((pend & 1) && __all((v0[1] == want) & (v0[3] == want))) {                 \
                    *(u64*)&htl[par_][pc][32*(4*wv+0) + 4*pm] = (u64)v0[0] | ((u64)v0[2] << 32); newly |= 1; } \
                if ((pend & 2) && __all((v1[1] == want) & (v1[3] == want))) {                 \
                    *(u64*)&htl[par_][pc][32*(4*wv+1) + 4*pm] = (u64)v1[0] | ((u64)v1[2] << 32); newly |= 2; } \
                if ((pend & 4) && __all((v2[1] == want) & (v2[3] == want))) {                 \
                    *(u64*)&htl[par_][pc][32*(4*wv+2) + 4*pm] = (u64)v2[0] | ((u64)v2[2] << 32); newly |= 4; } \
                if ((pend & 8) && __all((v3[1] == want) & (v3[3] == want))) {                 \
                    *(u64*)&htl[par_][pc][32*(4*wv+3) + 4*pm] = (u64)v3[0] | ((u64)v3[2] << 32); newly |= 8; } \
                if (newly) {                                                                  \
                    asm volatile("s_waitcnt lgkmcnt(0)" ::: "memory");                        \
                    if (lane == 0) {                                                          \
                        if (newly & 1) __hip_atomic_store(&hflag[4*wv+0], want, __ATOMIC_RELAXED, __HIP_MEMORY_SCOPE_WORKGROUP); \
                        if (newly & 2) __hip_atomic_store(&hflag[4*wv+1], want, __ATOMIC_RELAXED, __HIP_MEMORY_SCOPE_WORKGROUP); \
                        if (newly & 4) __hip_atomic_store(&hflag[4*wv+2], want, __ATOMIC_RELAXED, __HIP_MEMORY_SCOPE_WORKGROUP); \
                        if (newly & 8) __hip_atomic_store(&hflag[4*wv+3], want, __ATOMIC_RELAXED, __HIP_MEMORY_SCOPE_WORKGROUP); \
                    }                                                                         \
                    pend &= ~newly;                                                           \
                }                                                                             \
            } while (pend);                                                                   \
            if (colv < 8)                                                                     \
                out[(size_t)(t_ - 1) * (HH * BB) + hid * BB + g * GCOLS + colv] = hv_prev;    \
        }                                                                                     \
        /* (c) issue x_{t+2} loads into the other reg set (after all polls) */                \
        if (t_ + 2 < TT) {                                                                    \
            const float* xb_ = in_seq + (size_t)(t_ + 2) * (HH * BB)                          \
                             + (size_t)(tid * 2) * BB + g * GCOLS;                            \
            ROUT0 = *(const float4*)(xb_);      ROUT1 = *(const float4*)(xb_ + 4);            \
            ROUT2 = *(const float4*)(xb_ + BB); ROUT3 = *(const float4*)(xb_ + BB + 4);       \
        }                                                                                     \
        /* (d) h-half MFMAs, quad flag-gated */                                               \
        f32x4 aC = {0.f,0.f,0.f,0.f}, aD = {0.f,0.f,0.f,0.f};                                 \
        if (t_ > 0) {                                                                         \
            const u32 want = (u32)t_;                                                         \
            const u16 (*hc)[LDSK] = htl[par_];                                                \
            _Pragma("unroll")                                                                 \
            for (int J = 0; J < 4; ++J) {                                                     \
                const int qb = 4 * ((wv + J) & 3);                                            \
                if (J > 0) quad_spin(hflag, qb, want);                                        \
                short8 b0 = *(const short8*)&hc[lrow][(qb + 0) * 32 + lk8];                   \
                short8 b1 = *(const short8*)&hc[lrow][(qb + 1) * 32 + lk8];                   \
                short8 b2 = *(const short8*)&hc[lrow][(qb + 2) * 32 + lk8];                   \
                short8 b3 = *(const short8*)&hc[lrow][(qb + 3) * 32 + lk8];                   \
                aC = __builtin_amdgcn_mfma_f32_16x16x32_bf16(afrag[16+4*J+0], b0, aC, 0, 0, 0); \
                aD = __builtin_amdgcn_mfma_f32_16x16x32_bf16(afrag[16+4*J+1], b1, aD, 0, 0, 0); \
                aC = __builtin_amdgcn_mfma_f32_16x16x32_bf16(afrag[16+4*J+2], b2, aC, 0, 0, 0); \
                aD = __builtin_amdgcn_mfma_f32_16x16x32_bf16(afrag[16+4*J+3], b3, aD, 0, 0, 0); \
            }                                                                                 \
        }                                                                                     \
        f32x4 acc = (aA + aB) + (aC + aD);                                                    \
        /* (e) elementwise in-register; tagged h store */                                     \
        if (colv < 8) {                                                                       \
            float iv = fast_sigmoid(acc[0]);                                                  \
            float fv = fast_sigmoid(acc[1]);                                                  \
            float ov = fast_sigmoid(acc[2]);                                                  \
            float gv = fast_tanh(acc[3]);                                                     \
            cst = fv * cst + iv * gv;                                                         \
            float hv = ov * fast_tanh(cst);                                                   \
            u16 hb = f2bf(hv);                                                                \
            u32 up = (u32)__shfl_down((int)(u32)hb, 16);                                      \
            if ((q & 1) == 0) {                                                               \
                u64 pack = ((u64)(u32)(t_ + 1) << 32) | ((u64)(up & 0xffffu) << 16) | (u64)hb;\
                store_llc(htb + ((t_ + 1) & 1) * HTB_PAR + doff, pack);                       \
            }                                                                                 \
            hv_prev = hv;                                                                     \
            if (t_ == TT - 1) {                                                               \
                size_t base_ = (size_t)TT * HH * BB;                                          \
                out[base_ + hid * BB + g * GCOLS + colv] = hv;                                \
                out[base_ + HH * BB + hid * BB + g * GCOLS + colv] = cst;                     \
            }                                                                                 \
        }                                                                                     \
        /* (f) stage x_{t+1} from RIN (loaded one step ago); set own xflags */                \
        if (t_ + 1 < TT) {                                                                    \
            int k = tid * 2;                                                                  \
            u16 (*xn)[LDSK] = xt[(t_ + 1) & 1];                                               \
            const float *ra = (const float*)&RIN0, *rb = (const float*)&RIN2;                 \
            _Pragma("unroll")                                                                 \
            for (int j = 0; j < 4; ++j)                                                       \
                *(u32*)&xn[j][k] = (u32)f2bf(ra[j]) | ((u32)f2bf(rb[j]) << 16);               \
            const float *ra1 = (const float*)&RIN1, *rb1 = (const float*)&RIN3;               \
            _Pragma("unroll")                                                                 \
            for (int j = 0; j < 4; ++j)                                                       \
                *(u32*)&xn[4 + j][k] = (u32)f2bf(ra1[j]) | ((u32)f2bf(rb1[j]) << 16);         \
            asm volatile("s_waitcnt lgkmcnt(0)" ::: "memory");                                \
            if (lane == 0) {                                                                  \
                u32 nf = (u32)(t_ + 2);                                                       \
                __hip_atomic_store(&xflag[4*wv+0], nf, __ATOMIC_RELAXED, __HIP_MEMORY_SCOPE_WORKGROUP); \
                __hip_atomic_store(&xflag[4*wv+1], nf, __ATOMIC_RELAXED, __HIP_MEMORY_SCOPE_WORKGROUP); \
                __hip_atomic_store(&xflag[4*wv+2], nf, __ATOMIC_RELAXED, __HIP_MEMORY_SCOPE_WORKGROUP); \
                __hip_atomic_store(&xflag[4*wv+3], nf, __ATOMIC_RELAXED, __HIP_MEMORY_SCOPE_WORKGROUP); \
            }                                                                                 \
        }                                                                                     \
        /* (g) drain stores (mostly covered by (f)), then publish done-word */                \
        asm volatile("s_waitcnt vmcnt(0)" ::: "memory");                                      \
        if (lane == 0)                                                                        \
            store_llc32(dsum + ((t_ + 1) & 1) * DSUM_PAR + dsoff, (u32)(t_ + 1));             \
    }

    for (int t = 0; t < TT; t += 2) {
        LSTM_STEP(t,     xA0, xA1, xA2, xA3, xB0, xB1, xB2, xB3)
        LSTM_STEP(t + 1, xB0, xB1, xB2, xB3, xA0, xA1, xA2, xA3)
    }
#undef LSTM_STEP

    // flush deferred out[TT-1]
    if (colv < 8)
        out[(size_t)(TT - 1) * (HH * BB) + hid * BB + g * GCOLS + colv] = hv_prev;
}

extern "C" void kernel_launch(void* const* d_in, const int* in_sizes, int n_in,
                              void* d_out, int out_size, void* d_ws, size_t ws_size,
                              hipStream_t stream)
{
    const float* in_seq = (const float*)d_in[0];
    const float* Wxi = (const float*)d_in[1];
    const float* Wxf = (const float*)d_in[2];
    const float* Wxo = (const float*)d_in[3];
    const float* Wxg = (const float*)d_in[4];
    const float* Whi = (const float*)d_in[5];
    const float* Whf = (const float*)d_in[6];
    const float* Who = (const float*)d_in[7];
    const float* Whg = (const float*)d_in[8];

    u64* htb  = (u64*)d_ws;                       // 2*16384 u64 = 256 KiB, LLC-resident
    u32* dsum = (u32*)((u64*)d_ws + 2 * HTB_PAR); // 2048 u32 done-words

    lstm_prep<<<136, 256, 0, stream>>>(htb, dsum);  // re-zero tags+done each call
    lstm_persist<<<256, 256, 0, stream>>>(in_seq, Wxi, Wxf, Wxo, Wxg,
                                          Whi, Whf, Who, Whg,
                                          (float*)d_out, htb, dsum);
}

// Round 13
// 2350.968 us; speedup vs baseline: 1.5406x; 1.2425x over previous
//
#include <hip/hip_runtime.h>
#include <hip/hip_bf16.h>

typedef unsigned short u16;
typedef unsigned int   u32;
typedef unsigned long long u64;

typedef __attribute__((ext_vector_type(8))) short short8;
typedef __attribute__((ext_vector_type(4))) float f32x4;
typedef __attribute__((ext_vector_type(4))) u32   u32x4;

#define TT 1024
#define HH 512
#define BB 64
#define GCOLS 8
#define LDSK 528   // 264 dwords ≡ 8 mod 32 banks (measured best across 520/528/536)

// h exchange (LLC): u64 [2 parity][8 group][8 col][256 row-pair]
// u64 = tag<<32 | h[2rp+1]<<16 | h[2rp];  h produced at end of step t carries tag t+1
#define HTB_PAR 16384
#define HTB_GRP 2048

__device__ __forceinline__ u16 f2bf(float f) {
    union { float f; u32 u; } v; v.f = f;
    u32 u = v.u;
    return (u16)((u + 0x7FFFu + ((u >> 16) & 1u)) >> 16);
}

__device__ __forceinline__ short8 cvt8(const float4 &a, const float4 &b) {
    short8 r;
    r[0] = (short)f2bf(a.x); r[1] = (short)f2bf(a.y);
    r[2] = (short)f2bf(a.z); r[3] = (short)f2bf(a.w);
    r[4] = (short)f2bf(b.x); r[5] = (short)f2bf(b.y);
    r[6] = (short)f2bf(b.z); r[7] = (short)f2bf(b.w);
    return r;
}

__device__ __forceinline__ float fast_rcp(float x) {
    float r; asm("v_rcp_f32 %0, %1" : "=v"(r) : "v"(x)); return r;
}
__device__ __forceinline__ float fast_sigmoid(float x) { return fast_rcp(1.f + __expf(-x)); }
__device__ __forceinline__ float fast_tanh(float x) {
    float e = __expf(2.f * x);
    return 1.f - 2.f * fast_rcp(e + 1.f);
}

// pair flag spin, monotonic (flag >= want); broadcast LDS reads
__device__ __forceinline__ void pair_spin(const u32* fl, int pb, u32 want) {
    u32 f0, f1;
    do {
        f0 = __hip_atomic_load(&fl[pb + 0], __ATOMIC_RELAXED, __HIP_MEMORY_SCOPE_WORKGROUP);
        f1 = __hip_atomic_load(&fl[pb + 1], __ATOMIC_RELAXED, __HIP_MEMORY_SCOPE_WORKGROUP);
    } while (((int)(f0 - want) | (int)(f1 - want)) < 0);
    asm volatile("" ::: "memory");
}

// 2 chunk polls (16B each, 128B apart), LLC scope
__device__ __forceinline__ void poll_issue2(const u64* p, u32x4 &A, u32x4 &B) {
    asm volatile(
        "global_load_dwordx4 %0, %2, off sc0 sc1\n\t"
        "global_load_dwordx4 %1, %2, off offset:128 sc0 sc1"
        : "=&v"(A), "=&v"(B) : "v"(p) : "memory");
}
__device__ __forceinline__ void poll_wait2(u32x4 &A, u32x4 &B) {
    asm volatile("s_waitcnt vmcnt(0)" : "+v"(A), "+v"(B) :: "memory");
}
__device__ __forceinline__ void store_llc(u64* p, u64 v) {
    asm volatile("global_store_dwordx2 %0, %1, off sc0 sc1" :: "v"(p), "v"(v) : "memory");
}

__global__ void lstm_prep(u64* htb) {
    int i = blockIdx.x * 256 + threadIdx.x;   // 128*256 = 32768 u64 = full buffer
    __hip_atomic_store(&htb[i], 0ull, __ATOMIC_RELAXED, __HIP_MEMORY_SCOPE_AGENT);
}

__global__ __launch_bounds__(512, 2)
void lstm_persist(const float* __restrict__ in_seq,
                  const float* __restrict__ Wxi, const float* __restrict__ Wxf,
                  const float* __restrict__ Wxo, const float* __restrict__ Wxg,
                  const float* __restrict__ Whi, const float* __restrict__ Whf,
                  const float* __restrict__ Who, const float* __restrict__ Whg,
                  float* __restrict__ out, u64* htb)
{
    __shared__ u16 xt[2][16][LDSK];    // x B-operand, dbuf; cols 8..15 stay zero
    __shared__ u16 htl[2][16][LDSK];   // h B-operand, dbuf; cols 8..15 stay zero
    __shared__ u32 xflag[16];          // per-chunk: (step whose x is staged) + 1
    __shared__ u32 hflag[16];          // per-chunk: step whose h is staged

    const int tid  = threadIdx.x;
    const int bid  = blockIdx.x;
    const int g    = bid & 7;          // column group (8 groups x 16 WGs = 128 WGs)
    const int wgid = bid >> 3;         // 0..15: hidden rows [32*wgid, 32*wgid+32)
    const int wv   = tid >> 6;         // wave 0..7; owns chunks 2wv, 2wv+1 (x and h)
    const int lane = tid & 63;
    const int lrow = lane & 15;        // A tile row / B col
    const int lk8  = (lane >> 4) * 8;

    {   // zero LDS once
        u16* p0 = &xt[0][0][0]; u16* p1 = &htl[0][0][0];
        for (int i = tid; i < 2 * 16 * LDSK; i += 512) { p0[i] = 0; p1[i] = 0; }
        if (tid < 16) { xflag[tid] = 1; hflag[tid] = 0; }
    }

    // gate-interleaved A: tile row m = 4q + r -> hidden row wv*4+q, gate r.
    // Both halves in wave-rotated chunk order: afrag[2J+i] (x) / afrag[16+2J+i] (h)
    // hold chunk 2*((wv+J)&7)+i  -> compile-time register indices everywhere.
    const int gt   = lrow & 3;
    const int grow = wgid * 32 + wv * 4 + (lrow >> 2);
    const float* WxS = (gt == 0) ? Wxi : (gt == 1) ? Wxf : (gt == 2) ? Wxo : Wxg;
    const float* WhS = (gt == 0) ? Whi : (gt == 1) ? Whf : (gt == 2) ? Who : Whg;

    short8 afrag[32];
    #pragma unroll
    for (int J = 0; J < 8; ++J)
        #pragma unroll
        for (int i = 0; i < 2; ++i) {
            int kk = 2 * ((wv + J) & 7) + i;
            const float* sx = WxS + grow * HH + kk * 32 + lk8;
            const float* sh = WhS + grow * HH + kk * 32 + lk8;
            afrag[2 * J + i]      = cvt8(*(const float4*)sx, *(const float4*)(sx + 4));
            afrag[16 + 2 * J + i] = cvt8(*(const float4*)sh, *(const float4*)(sh + 4));
        }

    const int q    = lane >> 4;        // elementwise: hidden row wv*4+q
    const int colv = lrow;             // elementwise: batch col (valid < 8)
    const int hid  = wgid * 32 + wv * 4 + q;
    float cst = 0.f;
    float hv_prev = 0.f;

    // poll ownership: wave wv polls chunks 2wv,2wv+1; lane = (col pc, row-pair pair pm).
    // lane pm's dwordx4 covers rows 32c+4pm..+3 == exactly producer wave pm's output.
    const int pc    = lane >> 3;
    const int pm    = lane & 7;
    const int poffb = g * HTB_GRP + pc * 256 + 32 * wv + 2 * pm;
    const int doff  = g * HTB_GRP + colv * 256 + (hid >> 1);

    // x staging ownership: thread covers k rows 2kp..2kp+1, cols 4*half..4*half+3;
    // wave wv stages k in [64wv,64wv+64) == its own chunks 2wv,2wv+1.
    const int kp   = tid >> 1;
    const int half = tid & 1;

    // ---- prologue: stage x_0; barrier; issue x_1 into set A ----
    float4 xA0, xA1, xB0, xB1;
    {
        const float* xb = in_seq + (size_t)(2 * kp) * BB + g * GCOLS + 4 * half;
        float4 c0 = *(const float4*)xb;
        float4 c1 = *(const float4*)(xb + BB);
        const float *r0 = (const float*)&c0, *r1 = (const float*)&c1;
        #pragma unroll
        for (int j = 0; j < 4; ++j)
            *(u32*)&xt[0][4 * half + j][2 * kp] = (u32)f2bf(r0[j]) | ((u32)f2bf(r1[j]) << 16);
    }
    __syncthreads();   // one prologue barrier: LDS zero + x_0 + flags visible
    {
        const float* xb = in_seq + (size_t)(HH * BB) + (size_t)(2 * kp) * BB + g * GCOLS + 4 * half;
        xA0 = *(const float4*)xb;
        xA1 = *(const float4*)(xb + BB);
    }

#define LSTM_STEP(T, RIN0, RIN1, ROUT0, ROUT1)                                                \
    {                                                                                         \
        const int t_ = (T);                                                                   \
        const int par_ = t_ & 1;                                                              \
        /* (a) x-half MFMAs, pair flag-gated (own pair J=0 skips spin) */                     \
        f32x4 aA = {0.f,0.f,0.f,0.f}, aB = {0.f,0.f,0.f,0.f};                                 \
        {                                                                                     \
            const u32 wantx = (u32)(t_ + 1);                                                  \
            const u16 (*xc)[LDSK] = xt[par_];                                                 \
            _Pragma("unroll")                                                                 \
            for (int J = 0; J < 8; ++J) {                                                     \
                const int cb = 2 * ((wv + J) & 7);                                            \
                if (J > 0) pair_spin(xflag, cb, wantx);                                       \
                short8 b0 = *(const short8*)&xc[lrow][(cb + 0) * 32 + lk8];                   \
                short8 b1 = *(const short8*)&xc[lrow][(cb + 1) * 32 + lk8];                   \
                aA = __builtin_amdgcn_mfma_f32_16x16x32_bf16(afrag[2*J+0], b0, aA, 0, 0, 0);  \
                aB = __builtin_amdgcn_mfma_f32_16x16x32_bf16(afrag[2*J+1], b1, aB, 0, 0, 0);  \
            }                                                                                 \
        }                                                                                     \
        /* (f') stage x_{t+1} BEFORE the poll: overlaps producer store transit */             \
        if (t_ + 1 < TT) {                                                                    \
            u16 (*xn)[LDSK] = xt[(t_ + 1) & 1];                                               \
            const float *r0 = (const float*)&RIN0, *r1 = (const float*)&RIN1;                 \
            _Pragma("unroll")                                                                 \
            for (int j = 0; j < 4; ++j)                                                       \
                *(u32*)&xn[4 * half + j][2 * kp] = (u32)f2bf(r0[j]) | ((u32)f2bf(r1[j]) << 16);\
            asm volatile("s_waitcnt lgkmcnt(0)" ::: "memory");                                \
            if (lane == 0) {                                                                  \
                u32 nf = (u32)(t_ + 2);                                                       \
                __hip_atomic_store(&xflag[2*wv+0], nf, __ATOMIC_RELAXED, __HIP_MEMORY_SCOPE_WORKGROUP); \
                __hip_atomic_store(&xflag[2*wv+1], nf, __ATOMIC_RELAXED, __HIP_MEMORY_SCOPE_WORKGROUP); \
            }                                                                                 \
        }                                                                                     \
        /* (b) poll own 2 h chunks (LLC, tagged); stage + hflag; deferred out store */        \
        if (t_ > 0) {                                                                         \
            const u32 want = (u32)t_;                                                         \
            const u64* p_ = htb + par_ * HTB_PAR + poffb;                                     \
            u32x4 v0, v1;                                                                     \
            int pend = 3;                                                                     \
            do {                                                                              \
                poll_issue2(p_, v0, v1);                                                      \
                poll_wait2(v0, v1);                                                           \
                int newly = 0;                                                                \
                if ((pend & 1) && __all((v0[1] == want) & (v0[3] == want))) {                 \
                    *(u64*)&htl[par_][pc][32*(2*wv+0) + 4*pm] = (u64)v0[0] | ((u64)v0[2] << 32); newly |= 1; } \
                if ((pend & 2) && __all((v1[1] == want) & (v1[3] == want))) {                 \
                    *(u64*)&htl[par_][pc][32*(2*wv+1) + 4*pm] = (u64)v1[0] | ((u64)v1[2] << 32); newly |= 2; } \
                if (newly) {                                                                  \
                    asm volatile("s_waitcnt lgkmcnt(0)" ::: "memory");                        \
                    if (lane == 0) {                                                          \
                        if (newly & 1) __hip_atomic_store(&hflag[2*wv+0], want, __ATOMIC_RELAXED, __HIP_MEMORY_SCOPE_WORKGROUP); \
                        if (newly & 2) __hip_atomic_store(&hflag[2*wv+1], want, __ATOMIC_RELAXED, __HIP_MEMORY_SCOPE_WORKGROUP); \
                    }                                                                         \
                    pend &= ~newly;                                                           \
                }                                                                             \
            } while (pend);                                                                   \
            if (colv < 8)                                                                     \
                out[(size_t)(t_ - 1) * (HH * BB) + hid * BB + g * GCOLS + colv] = hv_prev;    \
        }                                                                                     \
        /* (c) issue x_{t+2} loads (strictly after polls: vmcnt retires in order) */          \
        if (t_ + 2 < TT) {                                                                    \
            const float* xb_ = in_seq + (size_t)(t_ + 2) * (HH * BB)                          \
                             + (size_t)(2 * kp) * BB + g * GCOLS + 4 * half;                  \
            ROUT0 = *(const float4*)xb_;                                                      \
            ROUT1 = *(const float4*)(xb_ + BB);                                               \
        }                                                                                     \
        /* (d) h-half MFMAs, pair flag-gated */                                               \
        f32x4 aC = {0.f,0.f,0.f,0.f}, aD = {0.f,0.f,0.f,0.f};                                 \
        if (t_ > 0) {                                                                         \
            const u32 want = (u32)t_;                                                         \
            const u16 (*hc)[LDSK] = htl[par_];                                                \
            _Pragma("unroll")                                                                 \
            for (int J = 0; J < 8; ++J) {                                                     \
                const int cb = 2 * ((wv + J) & 7);                                            \
                if (J > 0) pair_spin(hflag, cb, want);                                        \
                short8 b0 = *(const short8*)&hc[lrow][(cb + 0) * 32 + lk8];                   \
                short8 b1 = *(const short8*)&hc[lrow][(cb + 1) * 32 + lk8];                   \
                aC = __builtin_amdgcn_mfma_f32_16x16x32_bf16(afrag[16+2*J+0], b0, aC, 0, 0, 0); \
                aD = __builtin_amdgcn_mfma_f32_16x16x32_bf16(afrag[16+2*J+1], b1, aD, 0, 0, 0); \
            }                                                                                 \
        }                                                                                     \
        f32x4 acc = (aA + aB) + (aC + aD);                                                    \
        /* (e) elementwise in-register; tagged h store (no drain) */                          \
        if (colv < 8) {                                                                       \
            float iv = fast_sigmoid(acc[0]);                                                  \
            float fv = fast_sigmoid(acc[1]);                                                  \
            float ov = fast_sigmoid(acc[2]);                                                  \
            float gv = fast_tanh(acc[3]);                                                     \
            cst = fv * cst + iv * gv;                                                         \
            float hv = ov * fast_tanh(cst);                                                   \
            u16 hb = f2bf(hv);                                                                \
            u32 up = (u32)__shfl_down((int)(u32)hb, 16);   /* row hid+1 (q+1) */              \
            if ((q & 1) == 0) {                                                               \
                u64 pack = ((u64)(u32)(t_ + 1) << 32) | ((u64)(up & 0xffffu) << 16) | (u64)hb;\
                store_llc(htb + ((t_ + 1) & 1) * HTB_PAR + doff, pack);                       \
            }                                                                                 \
            hv_prev = hv;                                                                     \
            if (t_ == TT - 1) {                                                               \
                size_t base_ = (size_t)TT * HH * BB;                                          \
                out[base_ + hid * BB + g * GCOLS + colv] = hv;                                \
                out[base_ + HH * BB + hid * BB + g * GCOLS + colv] = cst;                     \
            }                                                                                 \
        }                                                                                     \
    }

    for (int t = 0; t < TT; t += 2) {
        LSTM_STEP(t,     xA0, xA1, xB0, xB1)
        LSTM_STEP(t + 1, xB0, xB1, xA0, xA1)
    }
#undef LSTM_STEP

    // flush deferred out[TT-1]
    if (colv < 8)
        out[(size_t)(TT - 1) * (HH * BB) + hid * BB + g * GCOLS + colv] = hv_prev;
}

extern "C" void kernel_launch(void* const* d_in, const int* in_sizes, int n_in,
                              void* d_out, int out_size, void* d_ws, size_t ws_size,
                              hipStream_t stream)
{
    const float* in_seq = (const float*)d_in[0];
    const float* Wxi = (const float*)d_in[1];
    const float* Wxf = (const float*)d_in[2];
    const float* Wxo = (const float*)d_in[3];
    const float* Wxg = (const float*)d_in[4];
    const float* Whi = (const float*)d_in[5];
    const float* Whf = (const float*)d_in[6];
    const float* Who = (const float*)d_in[7];
    const float* Whg = (const float*)d_in[8];

    u64* htb = (u64*)d_ws;   // 2*16384 u64 = 256 KiB, LLC-resident

    lstm_prep<<<128, 256, 0, stream>>>(htb);   // re-zero tags every call (pre-poison safety)
    lstm_persist<<<128, 512, 0, stream>>>(in_seq, Wxi, Wxf, Wxo, Wxg,
                                          Whi, Whf, Who, Whg,
                                          (float*)d_out, htb);
}